// Round 21
// baseline (44.551 us; speedup 1.0000x reference)
//
#include <hip/hip_runtime.h>
#include <math.h>

// Problem constants
#define BB   4
#define CIN  64
#define HH   64
#define WW   256
#define CO   128
#define NPIX (BB*HH*WW)       // 65536

typedef float  f32x4 __attribute__((ext_vector_type(4)));
typedef float  f32x16 __attribute__((ext_vector_type(16)));
typedef unsigned int u32x4 __attribute__((ext_vector_type(4)));
typedef _Float16 f16x8 __attribute__((ext_vector_type(8)));
typedef _Float16 f16x2 __attribute__((ext_vector_type(2)));

// Workspace layout (float/u32 slots). Total ~8.5 MB.
#define XTB_OFF  0
#define XTB_SZ   (NPIX*32)            // 2097152 u32: f16 x, TILED [b][y][xg][ch8][xl16]
#define OWB_OFF  (XTB_OFF + XTB_SZ)
#define OWB_SZ   9216                 // 18432 f16: offconv A-frags [9][4][64][8] (32x32)
#define WTF_OFF  (OWB_OFF + OWB_SZ)   // f16 [9][4][4][64][8]: main A-frags, lane-linear

// x tile addressing (u32x4 = 16B chunk units):
//   chunk(b,y,x,oct) = ((b*HH+y)*16 + (x>>4))*128 + oct*16 + (x&15), oct = ch-octet 0..7

// XCD-aware block swizzles (8 XCDs).
__device__ inline int xcd_swz(int bid)    { return (bid & 7) * 128 + (bid >> 3); }
__device__ inline int xcd_swz256(int bid) { return (bid & 7) * 32  + (bid >> 3); }

// ---------------------------------------------------------------------------
// K0: merged prep — blocks 0..1023: x -> tiled f16 xtb; blocks 1024..1039:
// weight prep into 32x32-MFMA A-fragment layouts (grid-stride).
__global__ __launch_bounds__(256) void k_prep(const float* __restrict__ x,
                                              const float* __restrict__ ow,
                                              const float* __restrict__ wm,
                                              unsigned int* __restrict__ xtb,
                                              unsigned short* __restrict__ owb,
                                              unsigned short* __restrict__ wtF) {
    __shared__ float t[64][65];
    int tid = threadIdx.x;
    if (blockIdx.x < 1024) {
        int bx = xcd_swz(blockIdx.x);  // (b, y, xtile)
        int x0 = (bx & 3) * 64;
        int y  = (bx >> 2) & 63;
        int b  = bx >> 8;
        int lx = tid & 63, gy = tid >> 6;
#pragma unroll
        for (int i = 0; i < 16; ++i) {
            int c = i * 4 + gy;
            t[c][lx] = x[((b*CIN + c)*HH + y)*WW + x0 + lx];
        }
        __syncthreads();
        int px = tid & 63, cg = tid >> 6;      // 16 channels per cg
        u32x4 r0, r1;
#pragma unroll
        for (int j = 0; j < 4; ++j) {
            f16x2 p, q;
            p[0] = (_Float16)t[cg*16 + 2*j][px];
            p[1] = (_Float16)t[cg*16 + 2*j + 1][px];
            q[0] = (_Float16)t[cg*16 + 8 + 2*j][px];
            q[1] = (_Float16)t[cg*16 + 8 + 2*j + 1][px];
            r0[j] = __builtin_bit_cast(unsigned int, p);
            r1[j] = __builtin_bit_cast(unsigned int, q);
        }
        int xx = x0 + px;
        int u = ((b*HH + y)*16 + (xx >> 4))*128 + (xx & 15);
        u32x4* dst = (u32x4*)xtb;
        dst[u + (2*cg)*16]     = r0;   // octet 2cg = ch cg*16..+7
        dst[u + (2*cg + 1)*16] = r1;   // octet 2cg+1 = ch cg*16+8..+15
    } else {
        const int n1 = 18432;          // owb: ((t*4+s)*64+l)*8+j
        const int n2 = 9*CO*CIN;       // wtF: (((t*4+s)*4+f)*64+l)*8+j
        for (int i = (blockIdx.x - 1024)*256 + tid; i < n1 + n2; i += 16*256) {
            if (i < n1) {
                int j = i & 7, l = (i >> 3) & 63, s = (i >> 9) & 3, tt = i >> 11;
                int oc = l & 31;
                int c  = s*16 + (l >> 5)*8 + j;
                float v = (oc < 27) ? ow[(oc*CIN + c)*9 + tt] : 0.f;
                owb[i] = __builtin_bit_cast(unsigned short, (_Float16)v);
            } else {
                int jj = i - n1;
                int j = jj & 7, l = (jj >> 3) & 63, f = (jj >> 9) & 3;
                int s = (jj >> 11) & 3, tt = jj >> 13;
                int oc = f*32 + (l & 31);
                int c  = s*16 + (l >> 5)*8 + j;
                float v = wm[(oc*CIN + c)*9 + tt];
                wtF[jj] = __builtin_bit_cast(unsigned short, (_Float16)v);
            }
        }
    }
}

// ---------------------------------------------------------------------------
__device__ inline f16x8 lerp8h(u32x4 a, u32x4 b, u32x4 c, u32x4 d,
                               f16x8 w0, f16x8 w1, f16x8 w2, f16x8 w3) {
    f16x8 av = __builtin_bit_cast(f16x8, a);
    f16x8 bv = __builtin_bit_cast(f16x8, b);
    f16x8 cv = __builtin_bit_cast(f16x8, c);
    f16x8 dv = __builtin_bit_cast(f16x8, d);
    return av*w0 + bv*w1 + cv*w2 + dv*w3;
}

__device__ inline f16x8 splat8(float s) {
    _Float16 h = (_Float16)s;
    return (f16x8){h, h, h, h, h, h, h, h};
}

// ---------------------------------------------------------------------------
// K2: FUSED offset-conv + sampling + GEMM, 32x32x16 MFMA (wave = 32 px x 128 oc).
// 256 blocks x 512 threads (8 waves = one 256-px row). LDS = 144KB weights +
// 14KB pscr = 158KB -> 8 waves/CU (2/SIMD, 256-VGPR budget, no spills).
// Per-px costs halve vs 16x16: LDS weight-read, addressing VALU, phase-A MFMA.
// A-frag layouts lane-linear (row=l&31, k=(l>>5)*8+j) -> conflict-free ds_read.
// C/D: col=l&31(px), row=(r&3)+8*(r>>2)+4*(l>>5)  [m74/m101 verified].
__global__ __launch_bounds__(512, 2) void k_fused(const unsigned int* __restrict__ xtb,
                                                  const unsigned short* __restrict__ owb,
                                                  const float* __restrict__ ob,
                                                  const unsigned short* __restrict__ wtF,
                                                  float* __restrict__ out) {
    __shared__ u32x4 wlds[9216];        // 144 KB: [9][4][4][64] lane-linear A-frags
    __shared__ _Float16 pscr[7168];     // 14 KB: [256 px][28] tap params (27 used)
    int bx = xcd_swz256(blockIdx.x);
    int ho = bx & 63, b = bx >> 6;
    int tid = threadIdx.x;
    int w = tid >> 6;              // 0..7 -> 32-px group
    int l = tid & 63;
    int pxw = l & 31, khalf = l >> 5;
    int wo = w*32 + pxw;

    const u32x4* xtb4 = (const u32x4*)xtb;
    int pbase = wo * 28;

    // ======== Phase A: offset conv (32 oc-rows x 32 px, one A-frag) ========
    {
        const u32x4* asrc = (const u32x4*)owb;
        f32x16 accA;
#pragma unroll
        for (int i = 0; i < 16; ++i) accA[i] = 0.f;
#pragma unroll
        for (int t = 0; t < 9; ++t) {
            int ki = t / 3, kj = t % 3;
            int y  = ho + ki - 1;
            int xx = wo + kj - 1;
            bool v = (y >= 0) && (y < HH) && (xx >= 0) && (xx < WW);
            int yc = min(max(y, 0), HH-1), xc = min(max(xx, 0), WW-1);
            int cb = ((b*HH + yc)*16 + (xc >> 4))*128 + (xc & 15);
#pragma unroll
            for (int s = 0; s < 4; ++s) {
                u32x4 bv = xtb4[cb + (s*2 + khalf)*16];
                if (!v) bv = (u32x4){0u,0u,0u,0u};
                u32x4 a = asrc[(t*4 + s)*64 + l];
                __builtin_amdgcn_s_setprio(1);
                accA = __builtin_amdgcn_mfma_f32_32x32x16_f16(
                           __builtin_bit_cast(f16x8, a), __builtin_bit_cast(f16x8, bv),
                           accA, 0, 0, 0);
                __builtin_amdgcn_s_setprio(0);
            }
        }
        // epilogue: bias + plane-permute + sigmoid -> f16 scratch (wave-local)
#pragma unroll
        for (int r = 0; r < 16; ++r) {
            int row = (r & 3) + 8*(r >> 2) + 4*khalf;     // 0..31
            if (row < 27) {
                float v = accA[r] + ob[row];
                if (row < 18) pscr[pbase + (row & 1)*9 + (row >> 1)] = (_Float16)v;
                else          pscr[pbase + row] = (_Float16)(1.f / (1.f + __expf(-v)));
            }
        }
    }
    // LDS ops within a wave complete in order -> phase B's reads of this wave's
    // own pscr entries are safe without a barrier (params are wave-local).

    // ======== stage main-conv weights (all 9 taps, lane-linear) ========
    const u32x4* wsrc = (const u32x4*)wtF;
#pragma unroll
    for (int i = 0; i < 18; ++i) wlds[tid + i*512] = wsrc[tid + i*512];

    // ======== Phase B: shallow-pipelined sampling + GEMM ========
    int   idx[2][4];     // corner chunk base (u32x4 units, sans oct*16), per tap&1
    float wts[2][4];     // bilinear*mask weights, per tap&1
    u32x4 G[2][4];       // gathered corners, per kstep&1
    float pdy0, pdx0, pm0, pdy1, pdx1, pm1;   // ping-pong (even/odd tap) params

    auto load_par0 = [&](int k) { pdy0 = (float)pscr[pbase+k]; pdx0 = (float)pscr[pbase+9+k]; pm0 = (float)pscr[pbase+18+k]; };
    auto load_par1 = [&](int k) { pdy1 = (float)pscr[pbase+k]; pdx1 = (float)pscr[pbase+9+k]; pm1 = (float)pscr[pbase+18+k]; };

    auto tap_addr = [&](int k, float dy, float dx, float m) {
        int ki = k / 3, kj = k - ki*3;
        float py  = dy + (float)(ho - 1 + ki);
        float pxf = dx + (float)(wo - 1 + kj);
        float y0f = floorf(py), x0f = floorf(pxf);
        float ly = py - y0f, lxf = pxf - x0f;
        int y0 = (int)y0f, x0 = (int)x0f;
        int y1 = y0 + 1,  x1 = x0 + 1;
        bool vy0 = (y0 >= 0) && (y0 < HH), vy1 = (y1 >= 0) && (y1 < HH);
        bool vx0 = (x0 >= 0) && (x0 < WW), vx1 = (x1 >= 0) && (x1 < WW);
        float hy = 1.f - ly, hx = 1.f - lxf;
        int s = k & 1;
        wts[s][0] = (vy0 && vx0) ? hy*hx*m : 0.f;
        wts[s][1] = (vy0 && vx1) ? hy*lxf*m : 0.f;
        wts[s][2] = (vy1 && vx0) ? ly*hx*m : 0.f;
        wts[s][3] = (vy1 && vx1) ? ly*lxf*m : 0.f;
        int yc0 = min(max(y0, 0), HH-1), yc1 = min(max(y1, 0), HH-1);
        int xc0 = min(max(x0, 0), WW-1), xc1 = min(max(x1, 0), WW-1);
        int rb0 = (b*HH + yc0)*16, rb1 = (b*HH + yc1)*16;
        idx[s][0] = (rb0 + (xc0 >> 4))*128 + (xc0 & 15);
        idx[s][1] = (rb0 + (xc1 >> 4))*128 + (xc1 & 15);
        idx[s][2] = (rb1 + (xc0 >> 4))*128 + (xc0 & 15);
        idx[s][3] = (rb1 + (xc1 >> 4))*128 + (xc1 & 15);
    };

    // ss = t*4 + s (tap t, k-step s): gather the 4 corners at this k-step's octet
    auto issue_ks = [&](int ss) {
        int t = ss >> 2, s = ss & 3;
        const int* id = idx[t & 1];
        u32x4* g = G[ss & 1];
        int oct = (s*2 + khalf) * 16;
        g[0] = xtb4[id[0] + oct];
        g[1] = xtb4[id[1] + oct];
        g[2] = xtb4[id[2] + oct];
        g[3] = xtb4[id[3] + oct];
    };

    // prologue: tap 0 addressed, k-step 0 in flight; tap 1's params loading
    load_par0(0);
    tap_addr(0, pdy0, pdx0, pm0);
    load_par1(1);
    issue_ks(0);

    // weight staging visible to all waves; gathers stay in flight (lgkm only)
    asm volatile("s_waitcnt lgkmcnt(0)\n\ts_barrier" ::: "memory");

    f32x16 acc[4];
#pragma unroll
    for (int f = 0; f < 4; ++f)
#pragma unroll
        for (int i = 0; i < 16; ++i) acc[f][i] = 0.f;

#pragma unroll
    for (int ss = 0; ss < 36; ++ss) {
        const int t = ss >> 2, s = ss & 3;
        // issue side: at the last k-step of tap t, compute tap t+1's addresses
        // from its pre-loaded params, then refill params for t+2 (ping-pong).
        if (s == 3 && t + 1 < 9) {
            if ((t + 1) & 1) tap_addr(t + 1, pdy1, pdx1, pm1);
            else             tap_addr(t + 1, pdy0, pdx0, pm0);
            if (t + 2 < 9) {
                if ((t + 2) & 1) load_par1(t + 2);
                else             load_par0(t + 2);
            }
        }
        if (ss + 1 < 36) issue_ks(ss + 1);

        // consume k-step ss: lerp -> one B fragment -> 4 MFMA (prio-boosted)
        const float* W = wts[t & 1];
        f16x8 bf = lerp8h(G[ss & 1][0], G[ss & 1][1], G[ss & 1][2], G[ss & 1][3],
                          splat8(W[0]), splat8(W[1]), splat8(W[2]), splat8(W[3]));
        __builtin_amdgcn_s_setprio(1);
#pragma unroll
        for (int f = 0; f < 4; ++f) {
            u32x4 a = wlds[((t*4 + s)*4 + f)*64 + l];
            acc[f] = __builtin_amdgcn_mfma_f32_32x32x16_f16(
                         __builtin_bit_cast(f16x8, a), bf, acc[f], 0, 0, 0);
        }
        __builtin_amdgcn_s_setprio(0);
    }

#pragma unroll
    for (int f = 0; f < 4; ++f)
#pragma unroll
        for (int r = 0; r < 16; ++r) {
            int o = f*32 + (r & 3) + 8*(r >> 2) + 4*khalf;
            out[((b*CO + o)*HH + ho)*WW + wo] = acc[f][r];
        }
}

// ---------------------------------------------------------------------------
extern "C" void kernel_launch(void* const* d_in, const int* in_sizes, int n_in,
                              void* d_out, int out_size, void* d_ws, size_t ws_size,
                              hipStream_t stream) {
    const float* x  = (const float*)d_in[0];
    const float* ow = (const float*)d_in[1];
    const float* ob = (const float*)d_in[2];
    const float* wm = (const float*)d_in[3];
    float* outp = (float*)d_out;

    float* ws   = (float*)d_ws;
    unsigned int* xtb = (unsigned int*)(ws + XTB_OFF);
    unsigned short* owb = (unsigned short*)(ws + OWB_OFF);
    unsigned short* wtF = (unsigned short*)(ws + WTF_OFF);

    k_prep<<<1040, 256, 0, stream>>>(x, ow, wm, xtb, owb, wtF);
    k_fused<<<256, 512, 0, stream>>>(xtb, owb, ob, wtF, outp);
}

// Round 22
// 41.456 us; speedup vs baseline: 1.0747x; 1.0747x over previous
//
#include <hip/hip_runtime.h>
#include <math.h>

// Problem constants
#define BB   4
#define CIN  64
#define HH   64
#define WW   256
#define CO   128
#define NPIX (BB*HH*WW)       // 65536

typedef float  f32x4 __attribute__((ext_vector_type(4)));
typedef unsigned int u32x4 __attribute__((ext_vector_type(4)));
typedef _Float16 f16x8 __attribute__((ext_vector_type(8)));
typedef _Float16 f16x2 __attribute__((ext_vector_type(2)));

// Workspace layout (float/u32 slots). Total ~8.5 MB.
#define XTB_OFF  0
#define XTB_SZ   (NPIX*32)            // 2097152 u32: f16 x, TILED [b][y][xg][ch8][xl16]
#define OWB_OFF  (XTB_OFF + XTB_SZ)
#define OWB_SZ   9216                 // 18432 f16: offconv A-fragments [18][2][64][8]
#define WTF_OFF  (OWB_OFF + OWB_SZ)   // ushort[9][8192] f16 A-frag, XOR-swizzled

// x tile addressing (u32x4 = 16B chunk units):
//   chunk(b,y,x,ch) = ((b*HH+y)*16 + (x>>4))*128 + ch*16 + (x&15),  ch = channel-octet 0..7
// One 64B line = 4 consecutive xl of the same (y,xg,ch): a wave's 16 px land in
// ~4-7 lines per gather (vs 16 in the old channel-major layout).

// XCD-aware block swizzles (8 XCDs).
__device__ inline int xcd_swz(int bid)    { return (bid & 7) * 128 + (bid >> 3); }
__device__ inline int xcd_swz256(int bid) { return (bid & 7) * 32  + (bid >> 3); }

// ---------------------------------------------------------------------------
// K0: merged prep — blocks 0..1023: x [B][C][H][W] f32 -> tiled f16 xtb;
//     blocks 1024..1039: weight prep (grid-stride). One dispatch.
__global__ __launch_bounds__(256) void k_prep(const float* __restrict__ x,
                                              const float* __restrict__ ow,
                                              const float* __restrict__ wm,
                                              unsigned int* __restrict__ xtb,
                                              unsigned short* __restrict__ owb,
                                              unsigned short* __restrict__ wtF) {
    __shared__ float t[64][65];
    int tid = threadIdx.x;
    if (blockIdx.x < 1024) {
        int bx = xcd_swz(blockIdx.x);  // (b, y, xtile)
        int x0 = (bx & 3) * 64;
        int y  = (bx >> 2) & 63;
        int b  = bx >> 8;
        int lx = tid & 63, gy = tid >> 6;
#pragma unroll
        for (int i = 0; i < 16; ++i) {
            int c = i * 4 + gy;
            t[c][lx] = x[((b*CIN + c)*HH + y)*WW + x0 + lx];
        }
        __syncthreads();
        int px = tid & 63, cg = tid >> 6;      // 16 channels per cg
        u32x4 r0, r1;
#pragma unroll
        for (int j = 0; j < 4; ++j) {
            f16x2 p, q;
            p[0] = (_Float16)t[cg*16 + 2*j][px];
            p[1] = (_Float16)t[cg*16 + 2*j + 1][px];
            q[0] = (_Float16)t[cg*16 + 8 + 2*j][px];
            q[1] = (_Float16)t[cg*16 + 8 + 2*j + 1][px];
            r0[j] = __builtin_bit_cast(unsigned int, p);
            r1[j] = __builtin_bit_cast(unsigned int, q);
        }
        // tiled store: pixel x0+px, ch-octets 2cg and 2cg+1
        int xx = x0 + px;
        int u = ((b*HH + y)*16 + (xx >> 4))*128 + (xx & 15);
        u32x4* dst = (u32x4*)xtb;
        dst[u + (2*cg)*16]     = r0;
        dst[u + (2*cg + 1)*16] = r1;
    } else {
        const int n1 = 18432;
        const int n2 = 9*CO*CIN;
        for (int i = (blockIdx.x - 1024)*256 + tid; i < n1 + n2; i += 16*256) {
            if (i < n1) {
                int j = i & 7, l = (i >> 3) & 63, mi = (i >> 9) & 1, kk = i >> 10;
                int oc = mi*16 + (l & 15);
                int k  = kk*32 + (l >> 4)*8 + j;
                int tt = k >> 6, c = k & 63;
                float v = (oc < 27) ? ow[(oc*CIN + c)*9 + tt] : 0.f;
                owb[i] = __builtin_bit_cast(unsigned short, (_Float16)v);
            } else {
                int j = i - n1;
                int k = j / (CO*CIN);
                int r = j % (CO*CIN);      // r = o*64 + c
                int o = r / CIN, c = r % CIN;
                float v = wm[(o*CIN + c)*9 + k];
                wtF[k*8192 + (r ^ ((o & 7) << 3))] =
                    __builtin_bit_cast(unsigned short, (_Float16)v);
            }
        }
    }
}

// ---------------------------------------------------------------------------
__device__ inline f16x8 lerp8h(u32x4 a, u32x4 b, u32x4 c, u32x4 d,
                               f16x8 w0, f16x8 w1, f16x8 w2, f16x8 w3) {
    f16x8 av = __builtin_bit_cast(f16x8, a);
    f16x8 bv = __builtin_bit_cast(f16x8, b);
    f16x8 cv = __builtin_bit_cast(f16x8, c);
    f16x8 dv = __builtin_bit_cast(f16x8, d);
    return av*w0 + bv*w1 + cv*w2 + dv*w3;
}

__device__ inline f16x8 splat8(float s) {
    _Float16 h = (_Float16)s;
    return (f16x8){h, h, h, h, h, h, h, h};
}

// ---------------------------------------------------------------------------
// K2: FUSED offset-conv + deformable sampling + f16 MFMA GEMM.
// 256 blocks x 1024 threads (16 waves, one 256-px row; wave = 16 px x 128 oc).
// x gathers use the TILED layout: one corner-gather touches ~5 lines, not 16.
__global__ __launch_bounds__(1024, 4) void k_fused(const unsigned int* __restrict__ xtb,
                                                   const unsigned short* __restrict__ owb,
                                                   const float* __restrict__ ob,
                                                   const unsigned short* __restrict__ wtF,
                                                   float* __restrict__ out) {
    __shared__ u32x4 wlds[9216];        // 144 KB: all 9 taps' main A-frags
    __shared__ _Float16 pscr[7168];     // 14 KB: [256 px][28] tap params (27 used)
    int bx = xcd_swz256(blockIdx.x);
    int ho = bx & 63, b = bx >> 6;
    int tid = threadIdx.x;
    int w = tid >> 6;              // 0..15 -> pixel group
    int l = tid & 63;
    int pxl = l & 15, hi = l >> 4;
    int wo = w*16 + pxl;

    const u32x4* xtb4 = (const u32x4*)xtb;
    int pbase = (w*16 + pxl) * 28;

    // ======== Phase A: offset conv for this wave's 16 px ========
    {
        const u32x4* asrc = (const u32x4*)owb;
        f32x4 acc0 = (f32x4){0.f,0.f,0.f,0.f}, acc1 = (f32x4){0.f,0.f,0.f,0.f};
#pragma unroll
        for (int kk = 0; kk < 18; ++kk) {
            const int t = kk >> 1;
            const int ki = t / 3, kj = t % 3;
            int y  = ho + ki - 1;
            int xx = wo + kj - 1;
            bool v = (y >= 0) && (y < HH) && (xx >= 0) && (xx < WW);
            int yc = min(max(y, 0), HH-1), xc = min(max(xx, 0), WW-1);
            u32x4 bv = xtb4[((b*HH + yc)*16 + (xc >> 4))*128
                            + ((kk & 1)*4 + hi)*16 + (xc & 15)];
            if (!v) bv = (u32x4){0u,0u,0u,0u};
            u32x4 a0 = asrc[(kk*2+0)*64 + l];
            u32x4 a1 = asrc[(kk*2+1)*64 + l];
            __builtin_amdgcn_s_setprio(1);
            acc0 = __builtin_amdgcn_mfma_f32_16x16x32_f16(
                       __builtin_bit_cast(f16x8, a0), __builtin_bit_cast(f16x8, bv), acc0, 0, 0, 0);
            acc1 = __builtin_amdgcn_mfma_f32_16x16x32_f16(
                       __builtin_bit_cast(f16x8, a1), __builtin_bit_cast(f16x8, bv), acc1, 0, 0, 0);
            __builtin_amdgcn_s_setprio(0);
        }
        // epilogue: bias + plane-permute + sigmoid -> f16 scratch (wave-local)
#pragma unroll
        for (int r = 0; r < 4; ++r) {
            int oc0 = hi*4 + r;                       // 0..15: dy/dx planes
            float v0 = acc0[r] + ob[oc0];
            pscr[pbase + (oc0 & 1)*9 + (oc0 >> 1)] = (_Float16)v0;
            int oc1 = 16 + hi*4 + r;                  // 16..31
            if (oc1 < 27) {
                float v1 = acc1[r] + ob[oc1];
                if (oc1 < 18) pscr[pbase + (oc1 & 1)*9 + (oc1 >> 1)] = (_Float16)v1;
                else          pscr[pbase + oc1] = (_Float16)(1.f / (1.f + __expf(-v1)));
            }
        }
    }
    // LDS ops within a wave complete in order -> this wave's reads below see
    // its own writes; params are wave-local (all 4 hi-lanes of px are here).

    // ======== stage main-conv weights (all 9 taps) ========
    const u32x4* wsrc = (const u32x4*)wtF;
#pragma unroll
    for (int i = 0; i < 9; ++i) wlds[tid + i*1024] = wsrc[tid + i*1024];

    // A-fragment swizzled LDS byte offsets (within a tap's 16KB)
    int lo0 = (hi*16)      ^ ((l & 7) << 4);
    int lo1 = (64 + hi*16) ^ ((l & 7) << 4);
    int abase = pxl * 128;

    // ======== Phase B: shallow-pipelined sampling + GEMM ========
    int   idx[2][4];     // corner chunk base (u32x4 units, sans ch*16), per tap&1
    float wts[2][4];     // bilinear*mask weights, per tap&1
    u32x4 G[2][4];       // gathered corners, per half&1
    float pdy0, pdx0, pm0, pdy1, pdx1, pm1;   // ping-pong (even/odd tap) params

    auto load_par0 = [&](int k) { pdy0 = (float)pscr[pbase+k]; pdx0 = (float)pscr[pbase+9+k]; pm0 = (float)pscr[pbase+18+k]; };
    auto load_par1 = [&](int k) { pdy1 = (float)pscr[pbase+k]; pdx1 = (float)pscr[pbase+9+k]; pm1 = (float)pscr[pbase+18+k]; };

    auto tap_addr = [&](int k, float dy, float dx, float m) {
        int ki = k / 3, kj = k - ki*3;
        float py  = dy + (float)(ho - 1 + ki);
        float pxf = dx + (float)(wo - 1 + kj);
        float y0f = floorf(py), x0f = floorf(pxf);
        float ly = py - y0f, lxf = pxf - x0f;
        int y0 = (int)y0f, x0 = (int)x0f;
        int y1 = y0 + 1,  x1 = x0 + 1;
        bool vy0 = (y0 >= 0) && (y0 < HH), vy1 = (y1 >= 0) && (y1 < HH);
        bool vx0 = (x0 >= 0) && (x0 < WW), vx1 = (x1 >= 0) && (x1 < WW);
        float hy = 1.f - ly, hx = 1.f - lxf;
        int s = k & 1;
        wts[s][0] = (vy0 && vx0) ? hy*hx*m : 0.f;
        wts[s][1] = (vy0 && vx1) ? hy*lxf*m : 0.f;
        wts[s][2] = (vy1 && vx0) ? ly*hx*m : 0.f;
        wts[s][3] = (vy1 && vx1) ? ly*lxf*m : 0.f;
        int yc0 = min(max(y0, 0), HH-1), yc1 = min(max(y1, 0), HH-1);
        int xc0 = min(max(x0, 0), WW-1), xc1 = min(max(x1, 0), WW-1);
        int rb0 = (b*HH + yc0)*16, rb1 = (b*HH + yc1)*16;
        idx[s][0] = (rb0 + (xc0 >> 4))*128 + (xc0 & 15);
        idx[s][1] = (rb0 + (xc1 >> 4))*128 + (xc1 & 15);
        idx[s][2] = (rb1 + (xc0 >> 4))*128 + (xc0 & 15);
        idx[s][3] = (rb1 + (xc1 >> 4))*128 + (xc1 & 15);
    };

    auto issue_half = [&](int h) {
        int k = h >> 1, p = h & 1;
        const int* id = idx[k & 1];
        u32x4* g = G[h & 1];
        int ch = (p*4 + hi) * 16;
        g[0] = xtb4[id[0] + ch];
        g[1] = xtb4[id[1] + ch];
        g[2] = xtb4[id[2] + ch];
        g[3] = xtb4[id[3] + ch];
    };

    // prologue: tap 0 addressed, half 0 in flight; tap 1's params loading
    load_par0(0);
    tap_addr(0, pdy0, pdx0, pm0);
    load_par1(1);
    issue_half(0);

    // weight staging visible to all waves; gathers stay in flight (lgkm only)
    asm volatile("s_waitcnt lgkmcnt(0)\n\ts_barrier" ::: "memory");

    f32x4 acc[8];
#pragma unroll
    for (int i = 0; i < 8; ++i) acc[i] = (f32x4){0.f, 0.f, 0.f, 0.f};

#pragma unroll
    for (int h = 0; h < 18; ++h) {
        const int t = h >> 1, p = h & 1;
        // issue side: at odd h (last half of tap t), compute tap t+1's
        // addresses from its pre-loaded params, then refill params for t+2.
        if ((h & 1) && (t + 1 < 9)) {
            if ((t + 1) & 1) tap_addr(t + 1, pdy1, pdx1, pm1);
            else             tap_addr(t + 1, pdy0, pdx0, pm0);
            if (t + 2 < 9) {
                if ((t + 2) & 1) load_par1(t + 2);
                else             load_par0(t + 2);
            }
        }
        if (h + 1 < 18) issue_half(h + 1);

        // consume half h: lerp -> one B fragment -> 8 MFMA (prio-boosted)
        const float* W = wts[t & 1];
        f16x8 bf = lerp8h(G[h & 1][0], G[h & 1][1], G[h & 1][2], G[h & 1][3],
                          splat8(W[0]), splat8(W[1]), splat8(W[2]), splat8(W[3]));
        const char* wb = (const char*)wlds + t*16384;
        const int lo = p ? lo1 : lo0;
        __builtin_amdgcn_s_setprio(1);
#pragma unroll
        for (int mi = 0; mi < 8; ++mi) {
            u32x4 a = *(const u32x4*)(wb + (abase + lo + mi*2048));
            acc[mi] = __builtin_amdgcn_mfma_f32_16x16x32_f16(
                          __builtin_bit_cast(f16x8, a), bf, acc[mi], 0, 0, 0);
        }
        __builtin_amdgcn_s_setprio(0);
    }

#pragma unroll
    for (int mi = 0; mi < 8; ++mi) {
#pragma unroll
        for (int r = 0; r < 4; ++r) {
            int o = mi*16 + hi*4 + r;     // C/D: col=lane&15(px), row=(lane>>4)*4+reg
            out[((b*CO + o)*HH + ho)*WW + wo] = acc[mi][r];
        }
    }
}

// ---------------------------------------------------------------------------
extern "C" void kernel_launch(void* const* d_in, const int* in_sizes, int n_in,
                              void* d_out, int out_size, void* d_ws, size_t ws_size,
                              hipStream_t stream) {
    const float* x  = (const float*)d_in[0];
    const float* ow = (const float*)d_in[1];
    const float* ob = (const float*)d_in[2];
    const float* wm = (const float*)d_in[3];
    float* outp = (float*)d_out;

    float* ws   = (float*)d_ws;
    unsigned int* xtb = (unsigned int*)(ws + XTB_OFF);
    unsigned short* owb = (unsigned short*)(ws + OWB_OFF);
    unsigned short* wtF = (unsigned short*)(ws + WTF_OFF);

    k_prep<<<1040, 256, 0, stream>>>(x, ow, wm, xtb, owb, wtF);
    k_fused<<<256, 1024, 0, stream>>>(xtb, owb, ob, wtF, outp);
}